// Round 1
// baseline (93.199 us; speedup 1.0000x reference)
//
#include <hip/hip_runtime.h>

#define SCALE 8
#define N_ 8
#define C_ 48
#define H_ 48
#define W_ 64
#define WT 16            // w-tile width
#define HO (H_*SCALE)    // 384
#define WO (W_*SCALE)    // 512

// out[n][c][h*8+p][w*8+q] = sum_k softmax_k(mask[n][k*64+p*8+q][h][w]) * inp_pad[n][c][h+di-1][w+dj-1]
// k = di*3+dj (row-major 3x3 taps, zero padding)
__global__ __launch_bounds__(256, 2) void raft_up_kernel(
    const float* __restrict__ inp, const float* __restrict__ mask,
    float* __restrict__ out)
{
    __shared__ float wgt[9 * 64 * WT];        // [k][sp=p*8+q][wi]  36 KB
    __shared__ float tin[C_ * 3 * (WT + 2)];  // [c][di][j]         10.1 KB

    const int t = threadIdx.x;
    const int bid = blockIdx.x;
    const int wblk = bid % (W_ / WT);
    const int h = (bid / (W_ / WT)) % H_;
    const int n = bid / ((W_ / WT) * H_);
    const int w0 = wblk * WT;

    // ---- Phase 0: stage input halo tile: tin[c][di][j] = inp[n][c][h+di-1][w0-1+j]
    for (int e = t; e < C_ * 3 * (WT + 2); e += 256) {
        int c   = e / (3 * (WT + 2));
        int rem = e % (3 * (WT + 2));
        int di  = rem / (WT + 2);
        int j   = rem % (WT + 2);
        int row = h + di - 1;
        int col = w0 - 1 + j;
        float v = 0.f;
        if (row >= 0 && row < H_ && col >= 0 && col < W_)
            v = inp[(((size_t)n * C_ + c) * H_ + row) * W_ + col];
        tin[e] = v;
    }

    // ---- Phase 1: softmax over 9 taps -> LDS weights
    // pairs: sp(64) x wi(WT) = 1024; 4 per thread; wi fastest across lanes (coalesced mask reads)
    #pragma unroll
    for (int r = 0; r < (64 * WT) / 256; ++r) {
        int pair = r * 256 + t;
        int wi = pair % WT;
        int sp = pair / WT;
        const float* mp = mask + (size_t)n * 576 * H_ * W_
                               + (size_t)sp * H_ * W_
                               + (size_t)h * W_ + w0 + wi;
        float v[9];
        float mx = -1e30f;
        #pragma unroll
        for (int k = 0; k < 9; ++k) {
            float x = mp[(size_t)k * 64 * H_ * W_];
            v[k] = x;
            mx = fmaxf(mx, x);
        }
        float s = 0.f;
        #pragma unroll
        for (int k = 0; k < 9; ++k) { v[k] = __expf(v[k] - mx); s += v[k]; }
        float inv = 1.f / s;
        #pragma unroll
        for (int k = 0; k < 9; ++k) wgt[(k * 64 + sp) * WT + wi] = v[k] * inv;
    }
    __syncthreads();

    // ---- Phase 2: thread owns (q, wi); loops channels; weights live in registers
    const int inner = t & 127;   // wi*8 + q  -> output column offset
    const int q  = inner & 7;
    const int wi = inner >> 3;   // 0..15
    const int half = t >> 7;     // channel half

    float wreg[9][8];            // [k][p]
    #pragma unroll
    for (int k = 0; k < 9; ++k)
        #pragma unroll
        for (int p = 0; p < 8; ++p)
            wreg[k][p] = wgt[(k * 64 + p * 8 + q) * WT + wi];

    float* outb = out + ((size_t)n * C_ * HO + (size_t)h * SCALE) * WO
                      + (size_t)w0 * SCALE + inner;

    for (int cc = 0; cc < 24; ++cc) {
        int c = half * 24 + cc;
        float tap[9];
        #pragma unroll
        for (int di = 0; di < 3; ++di)
            #pragma unroll
            for (int dj = 0; dj < 3; ++dj)
                tap[di * 3 + dj] = tin[(c * 3 + di) * (WT + 2) + wi + dj];
        #pragma unroll
        for (int p = 0; p < 8; ++p) {
            float acc = 0.f;
            #pragma unroll
            for (int k = 0; k < 9; ++k) acc = fmaf(wreg[k][p], tap[k], acc);
            outb[((size_t)c * HO + p) * WO] = acc;
        }
    }
}

extern "C" void kernel_launch(void* const* d_in, const int* in_sizes, int n_in,
                              void* d_out, int out_size, void* d_ws, size_t ws_size,
                              hipStream_t stream) {
    const float* inp  = (const float*)d_in[0];
    const float* mask = (const float*)d_in[1];
    float* out = (float*)d_out;
    const int blocks = N_ * H_ * (W_ / WT);  // 8*48*4 = 1536
    raft_up_kernel<<<blocks, 256, 0, stream>>>(inp, mask, out);
}